// Round 1
// baseline (379.191 us; speedup 1.0000x reference)
//
#include <hip/hip_runtime.h>
#include <hip/hip_bf16.h>
#include <stdint.h>

#define B_ 8
#define S_ 2048
#define E_ 768

typedef __attribute__((ext_vector_type(4))) float f32x4;
typedef __attribute__((ext_vector_type(8))) short bf16x8;

__device__ __forceinline__ unsigned short f2bf(float f) {
  union { float f; unsigned u; } v; v.f = f;
  unsigned r = v.u + 0x7FFFu + ((v.u >> 16) & 1u);
  return (unsigned short)(r >> 16);
}

// Stage a 128x32 bf16 tile (8192 B) from global (row stride ld elements) into LDS
// via global_load_lds dwordx4. 4 waves x 2 chunks x 64 lanes x 16 B = 8192 B.
__device__ __forceinline__ void stage_bf16(const unsigned short* __restrict__ gsrc, int ld,
                                           unsigned short* lds, int wid, int lane) {
#pragma unroll
  for (int ii = 0; ii < 2; ++ii) {
    const unsigned lin = (unsigned)(wid * 2 + ii) * 1024u + (unsigned)lane * 16u;
    const unsigned row = lin >> 6;   // 64 B per LDS row (32 bf16)
    const unsigned cb = lin & 63u;
    const char* g = (const char*)gsrc + (size_t)row * (size_t)ld * 2 + cb;
    __builtin_amdgcn_global_load_lds((const __attribute__((address_space(1))) void*)g,
                                     (__attribute__((address_space(3))) void*)((char*)lds + lin),
                                     16, 0, 0);
  }
}

// ---------------- K1: projection GEMM  O = X @ W^T + b  (f32 in, bf16 out) -----------
__global__ __launch_bounds__(256) void k_proj(const float* __restrict__ qin,
                                              const float* __restrict__ kin,
                                              const float* __restrict__ vin,
                                              const float* __restrict__ W,
                                              const float* __restrict__ bias,
                                              unsigned short* __restrict__ qp,
                                              unsigned short* __restrict__ kp,
                                              unsigned short* __restrict__ vp) {
  __shared__ __attribute__((aligned(16))) unsigned short As[128 * 32];
  __shared__ __attribute__((aligned(16))) unsigned short Bs[128 * 32];
  const int tid = threadIdx.x;
  const int lane = tid & 63;
  const int wid = tid >> 6;
  const int wr = (wid >> 1) * 64;
  const int wc = (wid & 1) * 64;
  const int r0 = blockIdx.x * 128;
  const int c0 = blockIdx.y * 128;
  const int z = blockIdx.z;
  const float* X = (z == 0) ? qin : ((z == 1) ? kin : vin);
  unsigned short* O = (z == 0) ? qp : ((z == 1) ? kp : vp);

  f32x4 acc[4][4] = {};

  for (int k0 = 0; k0 < E_; k0 += 32) {
#pragma unroll
    for (int i = 0; i < 4; ++i) {
      int f = i * 256 + tid;
      int row = f >> 3, c4 = f & 7;
      float4 a = *reinterpret_cast<const float4*>(&X[(size_t)(r0 + row) * E_ + k0 + c4 * 4]);
      float4 w = *reinterpret_cast<const float4*>(&W[(size_t)(c0 + row) * E_ + k0 + c4 * 4]);
      uint2 pa, pw;
      pa.x = (unsigned)f2bf(a.x) | ((unsigned)f2bf(a.y) << 16);
      pa.y = (unsigned)f2bf(a.z) | ((unsigned)f2bf(a.w) << 16);
      pw.x = (unsigned)f2bf(w.x) | ((unsigned)f2bf(w.y) << 16);
      pw.y = (unsigned)f2bf(w.z) | ((unsigned)f2bf(w.w) << 16);
      *reinterpret_cast<uint2*>(&As[row * 32 + c4 * 4]) = pa;
      *reinterpret_cast<uint2*>(&Bs[row * 32 + c4 * 4]) = pw;
    }
    __syncthreads();
    bf16x8 af[4], bfr[4];
#pragma unroll
    for (int m = 0; m < 4; ++m)
      af[m] = *reinterpret_cast<const bf16x8*>(&As[(wr + m * 16 + (lane & 15)) * 32 + (lane >> 4) * 8]);
#pragma unroll
    for (int n = 0; n < 4; ++n)
      bfr[n] = *reinterpret_cast<const bf16x8*>(&Bs[(wc + n * 16 + (lane & 15)) * 32 + (lane >> 4) * 8]);
#pragma unroll
    for (int m = 0; m < 4; ++m)
#pragma unroll
      for (int n = 0; n < 4; ++n)
        acc[m][n] = __builtin_amdgcn_mfma_f32_16x16x32_bf16(af[m], bfr[n], acc[m][n], 0, 0, 0);
    __syncthreads();
  }

#pragma unroll
  for (int n = 0; n < 4; ++n) {
    int gc = c0 + wc + n * 16 + (lane & 15);
    float bv = bias[gc];
#pragma unroll
    for (int m = 0; m < 4; ++m) {
      int gr = r0 + wr + m * 16 + (lane >> 4) * 4;
#pragma unroll
      for (int r = 0; r < 4; ++r) {
        O[(size_t)(gr + r) * E_ + gc] = f2bf(acc[m][n][r] + bv);
      }
    }
  }
}

// ---------------- K1b: transpose vp [B*S][E] -> vpT [B][E][S] ------------------------
__global__ __launch_bounds__(256) void k_vtrans(const unsigned short* __restrict__ vp,
                                                unsigned short* __restrict__ vpT) {
  __shared__ __attribute__((aligned(16))) unsigned short t[64][72];
  const int tid = threadIdx.x;
  const int st = blockIdx.x;  // s tile: 2048/64 = 32
  const int ot = blockIdx.y;  // o tile: 768/64 = 12
  const int b = blockIdx.z;
#pragma unroll
  for (int i = 0; i < 2; ++i) {
    int f = i * 256 + tid;  // 16B-unit index, 512 total
    int s = f >> 3, c8 = f & 7;
    uint4 vv = *reinterpret_cast<const uint4*>(
        &vp[((size_t)b * S_ + st * 64 + s) * E_ + ot * 64 + c8 * 8]);
    *reinterpret_cast<uint4*>(&t[s][c8 * 8]) = vv;
  }
  __syncthreads();
  const int o = tid >> 2;
  const int sb = (tid & 3) * 16;
  unsigned p[8];
#pragma unroll
  for (int j = 0; j < 8; ++j)
    p[j] = (unsigned)t[sb + 2 * j][o] | ((unsigned)t[sb + 2 * j + 1][o] << 16);
  uint4 w0 = make_uint4(p[0], p[1], p[2], p[3]);
  uint4 w1 = make_uint4(p[4], p[5], p[6], p[7]);
  size_t ob = ((size_t)b * E_ + ot * 64 + o) * S_ + st * 64 + sb;
  *reinterpret_cast<uint4*>(&vpT[ob]) = w0;
  *reinterpret_cast<uint4*>(&vpT[ob + 8]) = w1;
}

// ---------------- K2: scores = qp @ kp^T, mask, exp (unnormalized), rowsum ----------
__global__ __launch_bounds__(256) void k_scores(const unsigned short* __restrict__ qp,
                                                const unsigned short* __restrict__ kp,
                                                const int* __restrict__ mask,
                                                unsigned short* __restrict__ P,
                                                float* __restrict__ rowsum) {
  __shared__ __attribute__((aligned(16))) unsigned short As[128 * 32];
  __shared__ __attribute__((aligned(16))) unsigned short Bs[128 * 32];
  __shared__ float rlds[128][2];
  const int tid = threadIdx.x, lane = tid & 63, wid = tid >> 6;
  const int wr = (wid >> 1) * 64, wc = (wid & 1) * 64;
  const int qt = blockIdx.x, g = blockIdx.y, b = blockIdx.z;
  const unsigned short* Abase = qp + ((size_t)b * S_ + qt * 128) * E_;
  const float SC = (float)(1.4426950408889634 / 27.712812921102035);  // log2(e)/sqrt(768)
  float rs[4][4] = {{0.f}};

  for (int nt = 0; nt < 4; ++nt) {
    const int kv0 = g * 512 + nt * 128;
    const unsigned short* Bbase = kp + ((size_t)b * S_ + kv0) * E_;
    f32x4 acc[4][4] = {};
    for (int k0 = 0; k0 < E_; k0 += 32) {
      stage_bf16(Abase + k0, E_, As, wid, lane);
      stage_bf16(Bbase + k0, E_, Bs, wid, lane);
      __syncthreads();
      bf16x8 af[4], bfr[4];
#pragma unroll
      for (int m = 0; m < 4; ++m)
        af[m] = *reinterpret_cast<const bf16x8*>(&As[(wr + m * 16 + (lane & 15)) * 32 + (lane >> 4) * 8]);
#pragma unroll
      for (int n = 0; n < 4; ++n)
        bfr[n] = *reinterpret_cast<const bf16x8*>(&Bs[(wc + n * 16 + (lane & 15)) * 32 + (lane >> 4) * 8]);
#pragma unroll
      for (int m = 0; m < 4; ++m)
#pragma unroll
        for (int n = 0; n < 4; ++n)
          acc[m][n] = __builtin_amdgcn_mfma_f32_16x16x32_bf16(af[m], bfr[n], acc[m][n], 0, 0, 0);
      __syncthreads();
    }
#pragma unroll
    for (int m = 0; m < 4; ++m) {
#pragma unroll
      for (int r = 0; r < 4; ++r) {
        const int grow = qt * 128 + wr + m * 16 + (lane >> 4) * 4 + r;
        const size_t rowoff = ((size_t)b * S_ + grow) * S_;
        float radd = 0.f;
#pragma unroll
        for (int n = 0; n < 4; ++n) {
          const int gcol = kv0 + wc + n * 16 + (lane & 15);
          int mk = mask[rowoff + gcol];
          float pv = (mk == 1) ? 0.f : __builtin_amdgcn_exp2f(acc[m][n][r] * SC);
          radd += pv;
          P[rowoff + gcol] = f2bf(pv);
        }
        rs[m][r] += radd;
      }
    }
  }

#pragma unroll
  for (int m = 0; m < 4; ++m)
#pragma unroll
    for (int r = 0; r < 4; ++r) {
      float vsum = rs[m][r];
      vsum += __shfl_xor(vsum, 1);
      vsum += __shfl_xor(vsum, 2);
      vsum += __shfl_xor(vsum, 4);
      vsum += __shfl_xor(vsum, 8);
      if ((lane & 15) == 0) rlds[wr + m * 16 + (lane >> 4) * 4 + r][wid & 1] = vsum;
    }
  __syncthreads();
  if (tid < 128) {
    float tot = rlds[tid][0] + rlds[tid][1];
    rowsum[(size_t)g * (B_ * S_) + (size_t)b * S_ + qt * 128 + tid] = tot;
  }
}

// ---------------- K2b: inv_rs = 1 / sum_g rowsum ------------------------------------
__global__ __launch_bounds__(256) void k_invrs(const float* __restrict__ rowsum,
                                               float* __restrict__ inv_rs) {
  int i = blockIdx.x * 256 + threadIdx.x;
  float t = rowsum[i] + rowsum[16384 + i] + rowsum[2 * 16384 + i] + rowsum[3 * 16384 + i];
  inv_rs[i] = 1.0f / t;
}

// ---------------- K3: out = (P @ vpT^T) * inv_rs  (f32 out) -------------------------
__global__ __launch_bounds__(256) void k_pv(const unsigned short* __restrict__ P,
                                            const unsigned short* __restrict__ vpT,
                                            const float* __restrict__ inv_rs,
                                            float* __restrict__ out) {
  __shared__ __attribute__((aligned(16))) unsigned short As[128 * 32];
  __shared__ __attribute__((aligned(16))) unsigned short Bs[128 * 32];
  const int tid = threadIdx.x, lane = tid & 63, wid = tid >> 6;
  const int wr = (wid >> 1) * 64, wc = (wid & 1) * 64;
  const int mt = blockIdx.x, nt = blockIdx.y, b = blockIdx.z;
  const unsigned short* Abase = P + ((size_t)b * S_ + mt * 128) * S_;
  const unsigned short* Bbase = vpT + ((size_t)b * E_ + nt * 128) * S_;
  f32x4 acc[4][4] = {};
  for (int k0 = 0; k0 < S_; k0 += 32) {
    stage_bf16(Abase + k0, S_, As, wid, lane);
    stage_bf16(Bbase + k0, S_, Bs, wid, lane);
    __syncthreads();
    bf16x8 af[4], bfr[4];
#pragma unroll
    for (int m = 0; m < 4; ++m)
      af[m] = *reinterpret_cast<const bf16x8*>(&As[(wr + m * 16 + (lane & 15)) * 32 + (lane >> 4) * 8]);
#pragma unroll
    for (int n = 0; n < 4; ++n)
      bfr[n] = *reinterpret_cast<const bf16x8*>(&Bs[(wc + n * 16 + (lane & 15)) * 32 + (lane >> 4) * 8]);
#pragma unroll
    for (int m = 0; m < 4; ++m)
#pragma unroll
      for (int n = 0; n < 4; ++n)
        acc[m][n] = __builtin_amdgcn_mfma_f32_16x16x32_bf16(af[m], bfr[n], acc[m][n], 0, 0, 0);
    __syncthreads();
  }
#pragma unroll
  for (int m = 0; m < 4; ++m)
#pragma unroll
    for (int r = 0; r < 4; ++r) {
      const int grow = mt * 128 + wr + m * 16 + (lane >> 4) * 4 + r;
      const float inv = inv_rs[b * S_ + grow];
#pragma unroll
      for (int n = 0; n < 4; ++n) {
        const int gcol = nt * 128 + wc + n * 16 + (lane & 15);
        out[((size_t)b * S_ + grow) * E_ + gcol] = acc[m][n][r] * inv;
      }
    }
}

extern "C" void kernel_launch(void* const* d_in, const int* in_sizes, int n_in,
                              void* d_out, int out_size, void* d_ws, size_t ws_size,
                              hipStream_t stream) {
  const float* q = (const float*)d_in[0];
  const float* k = (const float*)d_in[1];
  const float* v = (const float*)d_in[2];
  const int* mask = (const int*)d_in[3];
  const float* W = (const float*)d_in[4];
  const float* bias = (const float*)d_in[5];
  float* out = (float*)d_out;
  char* ws = (char*)d_ws;

  // workspace layout (bytes)
  unsigned short* qp = (unsigned short*)(ws + 0);          //  24 MB
  unsigned short* kp = (unsigned short*)(ws + 25165824);   //  24 MB
  unsigned short* vpT = (unsigned short*)(ws + 50331648);  //  24 MB
  unsigned short* P = (unsigned short*)(ws + 75497472);    //  64 MiB
  unsigned short* vp_tmp = P;  // reused: consumed by k_vtrans before k_scores writes P
  float* rowsum = (float*)(ws + 142606336);                // 4*B*S f32
  float* inv_rs = (float*)(ws + 142868480);                // B*S f32
  (void)in_sizes; (void)n_in; (void)out_size; (void)ws_size;

  dim3 blk(256, 1, 1);
  k_proj<<<dim3(128, 6, 3), blk, 0, stream>>>(q, k, v, W, bias, qp, kp, vp_tmp);
  k_vtrans<<<dim3(32, 12, 8), blk, 0, stream>>>(vp_tmp, vpT);
  k_scores<<<dim3(16, 4, 8), blk, 0, stream>>>(qp, kp, mask, P, rowsum);
  k_invrs<<<dim3(64, 1, 1), blk, 0, stream>>>(rowsum, inv_rs);
  k_pv<<<dim3(16, 6, 8), blk, 0, stream>>>(P, vpT, inv_rs, out);
}